// Round 1
// baseline (583.787 us; speedup 1.0000x reference)
//
#include <hip/hip_runtime.h>
#include <cstdint>

#define BATCH 16
#define CH 1024
#define CIN 256
#define NSP 2048   // H*W = 64*32
#define BN_EPS 1e-5f

typedef _Float16 f16;
typedef f16   f16x8 __attribute__((ext_vector_type(8)));
typedef float f32x4 __attribute__((ext_vector_type(4)));

typedef __attribute__((address_space(3))) void lds_t;
typedef __attribute__((address_space(1))) const void gbl_t;

// async 16B/lane global->LDS (LDS dest = wave-uniform base + lane*16)
__device__ __forceinline__ void gld16(void* l, const void* g) {
    __builtin_amdgcn_global_load_lds((gbl_t*)g, (lds_t*)l, 16, 0, 0);
}

// ---------------------------------------------------------------------------
// P0: weights -> fp16; fold BN+bias into inv/off
// ---------------------------------------------------------------------------
__global__ __launch_bounds__(256) void k_prep(
    const float* __restrict__ tw, const float* __restrict__ pw,
    const float* __restrict__ gw, const float* __restrict__ ww,
    const float* __restrict__ wb, const float* __restrict__ gamma,
    const float* __restrict__ beta, const float* __restrict__ mean,
    const float* __restrict__ var,
    f16* __restrict__ w_all, float* __restrict__ inv_out, float* __restrict__ off_out)
{
    int id = blockIdx.x * 256 + threadIdx.x;
    if (id < 4 * 262144) {
        int sel = id >> 18, off = id & 262143;
        const float* src = sel == 0 ? tw : sel == 1 ? pw : sel == 2 ? gw : ww;
        w_all[id] = (f16)src[off];
    } else {
        int c = id - 4 * 262144;
        if (c < CH) {
            float iv = gamma[c] * rsqrtf(var[c] + BN_EPS);
            inv_out[c] = iv;
            off_out[c] = (wb[c] - mean[c]) * iv + beta[c];
        }
    }
}

// ---------------------------------------------------------------------------
// P1: x [B,C,N] fp32 -> xT [B,N,C] fp16
// ---------------------------------------------------------------------------
__global__ __launch_bounds__(256) void k_transpose_x(
    const float* __restrict__ x, f16* __restrict__ xT)
{
    __shared__ float tile[64 * 65];
    int t = threadIdx.x;
    int n0 = blockIdx.x * 64, c0 = blockIdx.y * 64, b = blockIdx.z;
    const float* xb = x + (size_t)b * CH * NSP;
    for (int k = 0; k < 4; ++k) {
        int id = t + 256 * k;
        int row = id >> 4, cc = id & 15;
        float4 v = *(const float4*)(xb + (size_t)(c0 + row) * NSP + n0 + cc * 4);
        tile[row * 65 + cc * 4 + 0] = v.x;
        tile[row * 65 + cc * 4 + 1] = v.y;
        tile[row * 65 + cc * 4 + 2] = v.z;
        tile[row * 65 + cc * 4 + 3] = v.w;
    }
    __syncthreads();
    f16* xTb = xT + (size_t)b * NSP * CH;
    for (int k = 0; k < 2; ++k) {
        int id = t + 256 * k;
        int n = id >> 3, c8 = id & 7;
        f16x8 o;
        #pragma unroll
        for (int j = 0; j < 8; ++j) o[j] = (f16)tile[(c8 * 8 + j) * 65 + n];
        *(f16x8*)(xTb + (size_t)(n0 + n) * CH + c0 + c8 * 8) = o;
    }
}

// ---------------------------------------------------------------------------
// K1: QKV projections, m97-style: BK=64, global_load_lds(16B) staging into
// XOR-swizzled unpadded LDS tiles. grid (N/64, B, 3); tile 64n x 256o.
// Swizzle: 16B chunk c of row r stored at position (c&24)|((c^r)&7).
// ---------------------------------------------------------------------------
__global__ __launch_bounds__(256, 3) void k_qkv(
    const f16* __restrict__ xT, const f16* __restrict__ w_all,
    const float* __restrict__ tb, const float* __restrict__ pb,
    const float* __restrict__ gb,
    f16* __restrict__ theta, f16* __restrict__ phiT, f16* __restrict__ gT)
{
    __shared__ char smem[40960];
    f16* a_lds = (f16*)smem;            // [64][64]  swizzled (8 KB)
    f16* b_lds = (f16*)(smem + 8192);   // [256][64] swizzled (32 KB)
    int t = threadIdx.x;
    int w = t >> 6, lane = t & 63, l15 = lane & 15, q = lane >> 4;
    int sw = l15 & 7;
    int n0 = blockIdx.x * 64, b = blockIdx.y, set = blockIdx.z;
    const f16* W  = w_all + (size_t)set * (CIN * CH);
    const f16* xA = xT + ((size_t)b * NSP + n0) * CH;

    int rA  = lane >> 3;             // row-in-window 0..7
    int ccs = (lane & 7) ^ rA;       // swizzled global chunk for this lane

    f32x4 acc[4][4];
    #pragma unroll
    for (int i = 0; i < 4; ++i)
        #pragma unroll
        for (int j = 0; j < 4; ++j) acc[i][j] = (f32x4){0.f, 0.f, 0.f, 0.f};

    for (int it = 0; it < 16; ++it) {
        // A tile: 64 x 64 f16 = 8 KB = 8 windows of 1KB; 2 per wave
        #pragma unroll
        for (int i = 0; i < 2; ++i) {
            int win = w * 2 + i;
            int n = win * 8 + rA;
            gld16((char*)a_lds + win * 1024,
                  xA + (size_t)n * CH + it * 64 + ccs * 8);
        }
        // B tile: 256 x 64 f16 = 32 KB = 32 windows; 8 per wave
        #pragma unroll
        for (int i = 0; i < 8; ++i) {
            int win = w * 8 + i;
            int o = win * 8 + rA;
            gld16((char*)b_lds + win * 1024,
                  W + (size_t)o * CH + it * 64 + ccs * 8);
        }
        __syncthreads();   // (drains the async loads)

        #pragma unroll
        for (int kl = 0; kl < 2; ++kl) {
            int c16 = kl * 4 + q;
            int pos = (c16 ^ sw) & 7;
            f16x8 af[4], bfr[4];
            #pragma unroll
            for (int tn = 0; tn < 4; ++tn)
                af[tn] = *(const f16x8*)(a_lds + (16 * tn + l15) * 64 + pos * 8);
            #pragma unroll
            for (int to = 0; to < 4; ++to)
                bfr[to] = *(const f16x8*)(b_lds + (64 * w + 16 * to + l15) * 64 + pos * 8);
            #pragma unroll
            for (int tn = 0; tn < 4; ++tn)
                #pragma unroll
                for (int to = 0; to < 4; ++to)
                    acc[tn][to] = __builtin_amdgcn_mfma_f32_16x16x32_f16(
                        af[tn], bfr[to], acc[tn][to], 0, 0, 0);
        }
        __syncthreads();
    }

    const float* bias = set == 0 ? tb : set == 1 ? pb : gb;
    float bv[4];
    #pragma unroll
    for (int to = 0; to < 4; ++to) bv[to] = bias[64 * w + 16 * to + l15];

    if (set < 2) {
        f16* e_lds = (f16*)smem;  // [64][256]
        #pragma unroll
        for (int tn = 0; tn < 4; ++tn)
            #pragma unroll
            for (int to = 0; to < 4; ++to)
                #pragma unroll
                for (int r = 0; r < 4; ++r)
                    e_lds[(16 * tn + 4 * q + r) * 256 + 64 * w + 16 * to + l15] =
                        (f16)(acc[tn][to][r] + bv[to]);
        __syncthreads();
        f16* dst = (set == 0 ? theta : phiT) + ((size_t)b * NSP + n0) * CIN;
        for (int k2 = 0; k2 < 8; ++k2) {
            int id = t + 256 * k2;
            *(f16x8*)(dst + id * 8) = *(const f16x8*)(e_lds + id * 8);
        }
    } else {
        f16* e_lds = (f16*)smem;  // [256][72]
        #pragma unroll
        for (int tn = 0; tn < 4; ++tn)
            #pragma unroll
            for (int to = 0; to < 4; ++to)
                #pragma unroll
                for (int r = 0; r < 4; ++r)
                    e_lds[(64 * w + 16 * to + l15) * 72 + 16 * tn + 4 * q + r] =
                        (f16)(acc[tn][to][r] + bv[to]);
        __syncthreads();
        f16* dst = gT + (size_t)b * CIN * NSP + n0;
        for (int k2 = 0; k2 < 8; ++k2) {
            int id = t + 256 * k2;
            int o = id >> 3, cc = id & 7;
            *(f16x8*)(dst + (size_t)o * NSP + cc * 8) = *(const f16x8*)(e_lds + o * 72 + cc * 8);
        }
    }
}

// ---------------------------------------------------------------------------
// K2: flash attention v2. Register-prefetch double-buffering, combined
// phi+gT staging, XOR-swizzled LDS, P aliased into phi region (3 barriers).
// grid (N/64, B); wave w owns q-rows [16w,16w+16).
// ---------------------------------------------------------------------------
__global__ __launch_bounds__(256, 2) void k_attn(
    const f16* __restrict__ theta, const f16* __restrict__ phiT,
    const f16* __restrict__ gT, f16* __restrict__ y)
{
    __shared__ char smem[65536];
    f16* phi_lds = (f16*)smem;               // [64][256] swizzled
    f16* g_lds   = (f16*)(smem + 32768);     // [256][64] swizzled
    f16* p_lds   = (f16*)smem;               // [64][72], alias over phi (after barrier B)
    int t = threadIdx.x;
    int w = t >> 6, lane = t & 63, l15 = lane & 15, q = lane >> 4;
    int sw = l15 & 7;
    int n0 = blockIdx.x * 64, b = blockIdx.y;

    f16x8 th[8];
    const f16* thp = theta + ((size_t)b * NSP + n0 + 16 * w + l15) * CIN + q * 8;
    #pragma unroll
    for (int kk = 0; kk < 8; ++kk) th[kk] = *(const f16x8*)(thp + kk * 32);

    f32x4 yacc[16];
    #pragma unroll
    for (int i = 0; i < 16; ++i) yacc[i] = (f32x4){0.f, 0.f, 0.f, 0.f};
    float mrow[4] = {-INFINITY, -INFINITY, -INFINITY, -INFINITY};
    float lrow[4] = {0.f, 0.f, 0.f, 0.f};

    const f16* phib = phiT + (size_t)b * NSP * CIN;
    const f16* gTb  = gT + (size_t)b * CIN * NSP;

    int tm5 = t >> 5, tc5 = t & 31;  // phi staging: m = tm5+8*k2, chunk tc5
    int to3 = t >> 3, tg7 = t & 7;   // gT staging: o = to3+32*k2, chunk tg7

    // prefetch tile 0 into registers
    f16x8 phr[8], gr[8];
    #pragma unroll
    for (int k2 = 0; k2 < 8; ++k2)
        phr[k2] = *(const f16x8*)(phib + (size_t)(t + 256 * k2) * 8);
    #pragma unroll
    for (int k2 = 0; k2 < 8; ++k2)
        gr[k2] = *(const f16x8*)(gTb + (size_t)(to3 + 32 * k2) * NSP + tg7 * 8);

    for (int it = 0; it < 32; ++it) {
        // stage regs -> LDS (swizzled)
        #pragma unroll
        for (int k2 = 0; k2 < 8; ++k2) {
            int m = tm5 + 8 * k2;
            int pos = (tc5 & 24) | ((tc5 ^ m) & 7);
            *(f16x8*)(phi_lds + m * 256 + pos * 8) = phr[k2];
        }
        #pragma unroll
        for (int k2 = 0; k2 < 8; ++k2) {
            int o = to3 + 32 * k2;
            int pos = (tg7 ^ o) & 7;
            *(f16x8*)(g_lds + o * 64 + pos * 8) = gr[k2];
        }
        __syncthreads();                               // [A]

        // prefetch next tile (hidden under S + softmax)
        if (it < 31) {
            const f16* ps = phib + (size_t)(it + 1) * 64 * CIN;
            #pragma unroll
            for (int k2 = 0; k2 < 8; ++k2)
                phr[k2] = *(const f16x8*)(ps + (size_t)(t + 256 * k2) * 8);
            const f16* gs = gTb + (size_t)(it + 1) * 64;
            #pragma unroll
            for (int k2 = 0; k2 < 8; ++k2)
                gr[k2] = *(const f16x8*)(gs + (size_t)(to3 + 32 * k2) * NSP + tg7 * 8);
        }

        // S = theta . phi^T
        f32x4 s[4];
        #pragma unroll
        for (int to = 0; to < 4; ++to) s[to] = (f32x4){0.f, 0.f, 0.f, 0.f};
        #pragma unroll
        for (int kk = 0; kk < 8; ++kk) {
            int c16 = kk * 4 + q;
            int pos = (c16 & 24) | ((c16 ^ sw) & 7);
            #pragma unroll
            for (int to = 0; to < 4; ++to) {
                f16x8 bfr = *(const f16x8*)(phi_lds + (16 * to + l15) * 256 + pos * 8);
                s[to] = __builtin_amdgcn_mfma_f32_16x16x32_f16(th[kk], bfr, s[to], 0, 0, 0);
            }
        }

        // online softmax (rows live on 16-lane groups sharing q)
        #pragma unroll
        for (int r = 0; r < 4; ++r) {
            float tm = fmaxf(fmaxf(s[0][r], s[1][r]), fmaxf(s[2][r], s[3][r]));
            #pragma unroll
            for (int msk = 1; msk < 16; msk <<= 1) tm = fmaxf(tm, __shfl_xor(tm, msk));
            float mnew  = fmaxf(mrow[r], tm);
            float alpha = __expf(mrow[r] - mnew);
            float rs = 0.f;
            #pragma unroll
            for (int to = 0; to < 4; ++to) {
                float p = __expf(s[to][r] - mnew);
                s[to][r] = p;
                rs += p;
            }
            #pragma unroll
            for (int msk = 1; msk < 16; msk <<= 1) rs += __shfl_xor(rs, msk);
            lrow[r] = lrow[r] * alpha + rs;
            mrow[r] = mnew;
            if (alpha != 1.0f) {   // skip when whole wave has no new max
                #pragma unroll
                for (int i = 0; i < 16; ++i) yacc[i][r] *= alpha;
            }
        }

        __syncthreads();                               // [B] phi reads done

        // P -> LDS (intra-wave region; read below by same wave, lgkm only)
        #pragma unroll
        for (int to = 0; to < 4; ++to)
            #pragma unroll
            for (int r = 0; r < 4; ++r)
                p_lds[(16 * w + 4 * q + r) * 72 + 16 * to + l15] = (f16)s[to][r];

        // PV
        #pragma unroll
        for (int kk2 = 0; kk2 < 2; ++kk2) {
            f16x8 pa = *(const f16x8*)(p_lds + (16 * w + l15) * 72 + kk2 * 32 + q * 8);
            int c16 = kk2 * 4 + q;
            int pos = (c16 ^ sw) & 7;
            #pragma unroll
            for (int tco = 0; tco < 16; ++tco) {
                f16x8 gfr = *(const f16x8*)(g_lds + (16 * tco + l15) * 64 + pos * 8);
                yacc[tco] = __builtin_amdgcn_mfma_f32_16x16x32_f16(pa, gfr, yacc[tco], 0, 0, 0);
            }
        }
        __syncthreads();                               // [C]
    }

    // epilogue: y = yacc / l, staged through phi region (plain [64][256])
    float invl[4];
    #pragma unroll
    for (int r = 0; r < 4; ++r) invl[r] = 1.0f / lrow[r];
    #pragma unroll
    for (int tco = 0; tco < 16; ++tco)
        #pragma unroll
        for (int r = 0; r < 4; ++r)
            phi_lds[(16 * w + 4 * q + r) * 256 + 16 * tco + l15] =
                (f16)(yacc[tco][r] * invl[r]);
    __syncthreads();
    f16* dst = y + ((size_t)b * NSP + n0) * CIN;
    for (int k2 = 0; k2 < 8; ++k2) {
        int id = t + 256 * k2;
        *(f16x8*)(dst + id * 8) = *(const f16x8*)(phi_lds + id * 8);
    }
}

// ---------------------------------------------------------------------------
// K3: Z = w_w . y^T, fused BN + residual. grid (N/64, C/64, B).
// New epilogue: stage acc tile through LDS as f32 [64][68] (16B-aligned rows,
// <=2-way banks), then fully-coalesced float4 x-load / out-store.
// ---------------------------------------------------------------------------
__global__ __launch_bounds__(256, 4) void k_out(
    const f16* __restrict__ yv, const f16* __restrict__ ww,
    const float* __restrict__ inv, const float* __restrict__ off,
    const float* __restrict__ x, float* __restrict__ out)
{
    __shared__ char smem[33792];            // union: y_lds f16[64*264] | z_lds f32[64*68]
    f16*   y_lds = (f16*)smem;
    float* z_lds = (float*)smem;
    int t = threadIdx.x;
    int w = t >> 6, lane = t & 63, l15 = lane & 15, q = lane >> 4;
    int n0 = blockIdx.x * 64, c0 = blockIdx.y * 64, b = blockIdx.z;

    const f16* src = yv + ((size_t)b * NSP + n0) * CIN;
    for (int k2 = 0; k2 < 8; ++k2) {
        int id = t + 256 * k2;
        int n = id >> 5, cc = id & 31;
        *(f16x8*)(y_lds + n * 264 + cc * 8) = *(const f16x8*)(src + id * 8);
    }
    __syncthreads();

    f32x4 acc[4];
    #pragma unroll
    for (int i = 0; i < 4; ++i) acc[i] = (f32x4){0.f, 0.f, 0.f, 0.f};
    const f16* wp = ww + (size_t)c0 * CIN + q * 8;
    #pragma unroll
    for (int kk = 0; kk < 8; ++kk) {
        f16x8 bfr = *(const f16x8*)(y_lds + (16 * w + l15) * 264 + kk * 32 + q * 8);
        #pragma unroll
        for (int tc = 0; tc < 4; ++tc) {
            f16x8 af = *(const f16x8*)(wp + (size_t)(16 * tc + l15) * CIN + kk * 32);
            acc[tc] = __builtin_amdgcn_mfma_f32_16x16x32_f16(af, bfr, acc[tc], 0, 0, 0);
        }
    }

    __syncthreads();   // y_lds reads done; reuse smem as f32 z tile

    // acc[tc][r]: c_local = 16tc+4q+r, n_local = 16w+l15. Stride 68 floats:
    // banks = (16q + l15 + const) mod 32 -> 2-way max (free).
    #pragma unroll
    for (int tc = 0; tc < 4; ++tc)
        #pragma unroll
        for (int r = 0; r < 4; ++r)
            z_lds[(16 * tc + 4 * q + r) * 68 + 16 * w + l15] = acc[tc][r];
    __syncthreads();

    // coalesced epilogue: 16 threads per c-row, each owns 4 consecutive n.
    #pragma unroll
    for (int k2 = 0; k2 < 4; ++k2) {
        int f  = t + 256 * k2;
        int cl = f >> 4, n4 = f & 15;
        int c  = c0 + cl;
        float4 z = *(const float4*)(z_lds + cl * 68 + n4 * 4);
        size_t idx = ((size_t)b * CH + c) * NSP + n0 + n4 * 4;
        float4 xv = *(const float4*)(x + idx);
        float iv = inv[c], ov = off[c];
        float4 o;
        o.x = z.x * iv + ov + xv.x;
        o.y = z.y * iv + ov + xv.y;
        o.z = z.z * iv + ov + xv.z;
        o.w = z.w * iv + ov + xv.w;
        *(float4*)(out + idx) = o;
    }
}

// ---------------------------------------------------------------------------
extern "C" void kernel_launch(void* const* d_in, const int* in_sizes, int n_in,
                              void* d_out, int out_size, void* d_ws, size_t ws_size,
                              hipStream_t stream)
{
    const float* x     = (const float*)d_in[0];
    const float* tw    = (const float*)d_in[1];
    const float* tb    = (const float*)d_in[2];
    const float* pw    = (const float*)d_in[3];
    const float* pb    = (const float*)d_in[4];
    const float* gw    = (const float*)d_in[5];
    const float* gb_   = (const float*)d_in[6];
    const float* ww    = (const float*)d_in[7];
    const float* wb    = (const float*)d_in[8];
    const float* gamma = (const float*)d_in[9];
    const float* beta  = (const float*)d_in[10];
    const float* mean  = (const float*)d_in[11];
    const float* var   = (const float*)d_in[12];
    float* out = (float*)d_out;

    char* ws = (char*)d_ws;
    f16* xT    = (f16*)ws;                    //  67108864 B
    f16* theta = (f16*)(ws + 67108864);       //  16777216 B
    f16* phiT  = (f16*)(ws + 83886080);       //  16777216 B
    f16* gT    = (f16*)(ws + 100663296);      //  16777216 B
    f16* yv    = (f16*)(ws + 117440512);      //  16777216 B
    f16* w_all = (f16*)(ws + 134217728);      //  4*524288 B
    float* inv  = (float*)(ws + 136314880);   //  4096 B
    float* offv = (float*)(ws + 136318976);   //  4096 B

    k_prep<<<4100, 256, 0, stream>>>(tw, pw, gw, ww, wb, gamma, beta, mean, var,
                                     w_all, inv, offv);
    k_transpose_x<<<dim3(32, 16, 16), 256, 0, stream>>>(x, xT);
    k_qkv<<<dim3(32, 16, 3), 256, 0, stream>>>(xT, w_all, tb, pb, gb_, theta, phiT, gT);
    k_attn<<<dim3(32, 16), 256, 0, stream>>>(theta, phiT, gT, yv);
    k_out<<<dim3(32, 16, 16), 256, 0, stream>>>(yv, w_all + 3 * 262144, inv, offv, x, out);
}

// Round 2
// 560.035 us; speedup vs baseline: 1.0424x; 1.0424x over previous
//
#include <hip/hip_runtime.h>
#include <cstdint>

#define BATCH 16
#define CH 1024
#define CIN 256
#define NSP 2048   // H*W = 64*32
#define BN_EPS 1e-5f

typedef _Float16 f16;
typedef f16   f16x8 __attribute__((ext_vector_type(8)));
typedef float f32x4 __attribute__((ext_vector_type(4)));

typedef __attribute__((address_space(3))) void lds_t;
typedef __attribute__((address_space(1))) const void gbl_t;

// async 16B/lane global->LDS (LDS dest = wave-uniform base + lane*16)
__device__ __forceinline__ void gld16(void* l, const void* g) {
    __builtin_amdgcn_global_load_lds((gbl_t*)g, (lds_t*)l, 16, 0, 0);
}

// ---------------------------------------------------------------------------
// P0: weights -> fp16; fold BN+bias into inv/off
// ---------------------------------------------------------------------------
__global__ __launch_bounds__(256) void k_prep(
    const float* __restrict__ tw, const float* __restrict__ pw,
    const float* __restrict__ gw, const float* __restrict__ ww,
    const float* __restrict__ wb, const float* __restrict__ gamma,
    const float* __restrict__ beta, const float* __restrict__ mean,
    const float* __restrict__ var,
    f16* __restrict__ w_all, float* __restrict__ inv_out, float* __restrict__ off_out)
{
    int id = blockIdx.x * 256 + threadIdx.x;
    if (id < 4 * 262144) {
        int sel = id >> 18, off = id & 262143;
        const float* src = sel == 0 ? tw : sel == 1 ? pw : sel == 2 ? gw : ww;
        w_all[id] = (f16)src[off];
    } else {
        int c = id - 4 * 262144;
        if (c < CH) {
            float iv = gamma[c] * rsqrtf(var[c] + BN_EPS);
            inv_out[c] = iv;
            off_out[c] = (wb[c] - mean[c]) * iv + beta[c];
        }
    }
}

// ---------------------------------------------------------------------------
// P1: x [B,C,N] fp32 -> xT [B,N,C] fp16
// ---------------------------------------------------------------------------
__global__ __launch_bounds__(256) void k_transpose_x(
    const float* __restrict__ x, f16* __restrict__ xT)
{
    __shared__ float tile[64 * 65];
    int t = threadIdx.x;
    int n0 = blockIdx.x * 64, c0 = blockIdx.y * 64, b = blockIdx.z;
    const float* xb = x + (size_t)b * CH * NSP;
    for (int k = 0; k < 4; ++k) {
        int id = t + 256 * k;
        int row = id >> 4, cc = id & 15;
        float4 v = *(const float4*)(xb + (size_t)(c0 + row) * NSP + n0 + cc * 4);
        tile[row * 65 + cc * 4 + 0] = v.x;
        tile[row * 65 + cc * 4 + 1] = v.y;
        tile[row * 65 + cc * 4 + 2] = v.z;
        tile[row * 65 + cc * 4 + 3] = v.w;
    }
    __syncthreads();
    f16* xTb = xT + (size_t)b * NSP * CH;
    for (int k = 0; k < 2; ++k) {
        int id = t + 256 * k;
        int n = id >> 3, c8 = id & 7;
        f16x8 o;
        #pragma unroll
        for (int j = 0; j < 8; ++j) o[j] = (f16)tile[(c8 * 8 + j) * 65 + n];
        *(f16x8*)(xTb + (size_t)(n0 + n) * CH + c0 + c8 * 8) = o;
    }
}

// ---------------------------------------------------------------------------
// K1: QKV projections, m97-style: BK=64, global_load_lds(16B) staging into
// XOR-swizzled unpadded LDS tiles. grid (N/64, B, 3); tile 64n x 256o.
// ---------------------------------------------------------------------------
__global__ __launch_bounds__(256, 3) void k_qkv(
    const f16* __restrict__ xT, const f16* __restrict__ w_all,
    const float* __restrict__ tb, const float* __restrict__ pb,
    const float* __restrict__ gb,
    f16* __restrict__ theta, f16* __restrict__ phiT, f16* __restrict__ gT)
{
    __shared__ char smem[40960];
    f16* a_lds = (f16*)smem;            // [64][64]  swizzled (8 KB)
    f16* b_lds = (f16*)(smem + 8192);   // [256][64] swizzled (32 KB)
    int t = threadIdx.x;
    int w = t >> 6, lane = t & 63, l15 = lane & 15, q = lane >> 4;
    int sw = l15 & 7;
    int n0 = blockIdx.x * 64, b = blockIdx.y, set = blockIdx.z;
    const f16* W  = w_all + (size_t)set * (CIN * CH);
    const f16* xA = xT + ((size_t)b * NSP + n0) * CH;

    int rA  = lane >> 3;             // row-in-window 0..7
    int ccs = (lane & 7) ^ rA;       // swizzled global chunk for this lane

    f32x4 acc[4][4];
    #pragma unroll
    for (int i = 0; i < 4; ++i)
        #pragma unroll
        for (int j = 0; j < 4; ++j) acc[i][j] = (f32x4){0.f, 0.f, 0.f, 0.f};

    for (int it = 0; it < 16; ++it) {
        #pragma unroll
        for (int i = 0; i < 2; ++i) {
            int win = w * 2 + i;
            int n = win * 8 + rA;
            gld16((char*)a_lds + win * 1024,
                  xA + (size_t)n * CH + it * 64 + ccs * 8);
        }
        #pragma unroll
        for (int i = 0; i < 8; ++i) {
            int win = w * 8 + i;
            int o = win * 8 + rA;
            gld16((char*)b_lds + win * 1024,
                  W + (size_t)o * CH + it * 64 + ccs * 8);
        }
        __syncthreads();

        #pragma unroll
        for (int kl = 0; kl < 2; ++kl) {
            int c16 = kl * 4 + q;
            int pos = (c16 ^ sw) & 7;
            f16x8 af[4], bfr[4];
            #pragma unroll
            for (int tn = 0; tn < 4; ++tn)
                af[tn] = *(const f16x8*)(a_lds + (16 * tn + l15) * 64 + pos * 8);
            #pragma unroll
            for (int to = 0; to < 4; ++to)
                bfr[to] = *(const f16x8*)(b_lds + (64 * w + 16 * to + l15) * 64 + pos * 8);
            #pragma unroll
            for (int tn = 0; tn < 4; ++tn)
                #pragma unroll
                for (int to = 0; to < 4; ++to)
                    acc[tn][to] = __builtin_amdgcn_mfma_f32_16x16x32_f16(
                        af[tn], bfr[to], acc[tn][to], 0, 0, 0);
        }
        __syncthreads();
    }

    const float* bias = set == 0 ? tb : set == 1 ? pb : gb;
    float bv[4];
    #pragma unroll
    for (int to = 0; to < 4; ++to) bv[to] = bias[64 * w + 16 * to + l15];

    if (set < 2) {
        f16* e_lds = (f16*)smem;  // [64][256]
        #pragma unroll
        for (int tn = 0; tn < 4; ++tn)
            #pragma unroll
            for (int to = 0; to < 4; ++to)
                #pragma unroll
                for (int r = 0; r < 4; ++r)
                    e_lds[(16 * tn + 4 * q + r) * 256 + 64 * w + 16 * to + l15] =
                        (f16)(acc[tn][to][r] + bv[to]);
        __syncthreads();
        f16* dst = (set == 0 ? theta : phiT) + ((size_t)b * NSP + n0) * CIN;
        for (int k2 = 0; k2 < 8; ++k2) {
            int id = t + 256 * k2;
            *(f16x8*)(dst + id * 8) = *(const f16x8*)(e_lds + id * 8);
        }
    } else {
        f16* e_lds = (f16*)smem;  // [256][72]
        #pragma unroll
        for (int tn = 0; tn < 4; ++tn)
            #pragma unroll
            for (int to = 0; to < 4; ++to)
                #pragma unroll
                for (int r = 0; r < 4; ++r)
                    e_lds[(64 * w + 16 * to + l15) * 72 + 16 * tn + 4 * q + r] =
                        (f16)(acc[tn][to][r] + bv[to]);
        __syncthreads();
        f16* dst = gT + (size_t)b * CIN * NSP + n0;
        for (int k2 = 0; k2 < 8; ++k2) {
            int id = t + 256 * k2;
            int o = id >> 3, cc = id & 7;
            *(f16x8*)(dst + (size_t)o * NSP + cc * 8) = *(const f16x8*)(e_lds + o * 72 + cc * 8);
        }
    }
}

// ---------------------------------------------------------------------------
// K2: flash attention v3. KVBLK=32, async gld16 double-buffered staging,
// swapped QK^T (S^T via A=phi, B=theta-in-regs) -> in-thread softmax with
// 2 shfl_xor rounds; ONE barrier per iteration. grid (N/64, B).
// LDS: phi dbuf 2x16K [32][256] swz | g dbuf 2x16K [256][32] swz | p 5K.
// ---------------------------------------------------------------------------
__global__ __launch_bounds__(256, 2) void k_attn(
    const f16* __restrict__ theta, const f16* __restrict__ phiT,
    const f16* __restrict__ gT, f16* __restrict__ y)
{
    __shared__ char smem[70656];
    f16* p_lds = (f16*)(smem + 65536);       // [64][40]
    int t = threadIdx.x;
    int w = t >> 6, lane = t & 63, l15 = lane & 15, q = lane >> 4;
    int n0 = blockIdx.x * 64, b = blockIdx.y;

    // theta in regs: valid directly as the MFMA B-operand (col = l15 = q-row)
    f16x8 th[8];
    const f16* thp = theta + ((size_t)b * NSP + n0 + 16 * w + l15) * CIN + q * 8;
    #pragma unroll
    for (int kk = 0; kk < 8; ++kk) th[kk] = *(const f16x8*)(thp + kk * 32);

    f32x4 yacc[16];
    #pragma unroll
    for (int i = 0; i < 16; ++i) yacc[i] = (f32x4){0.f, 0.f, 0.f, 0.f};
    float m_run = -INFINITY, l_run = 0.f;

    const f16* phib = phiT + (size_t)b * NSP * CIN;
    const f16* gTb  = gT + (size_t)b * CIN * NSP;

    // staging lane decomposition
    int prow_in = lane >> 5;   // phi: row within 2-row window
    int pchunk  = lane & 31;   // phi: 16B slot within 512B row
    int grow_in = lane >> 2;   // g: o-row within 16-row window
    int gslot   = lane & 3;    // g: 16B slot within 64B row

    auto stage = [&](int it, int bufsel) {
        char* pbuf = smem + bufsel * 16384;
        char* gbuf = smem + 32768 + bufsel * 16384;
        const f16* psrc = phib + (size_t)(it * 32) * CIN;
        #pragma unroll
        for (int i = 0; i < 4; ++i) {
            int win = w * 4 + i;
            int row = win * 2 + prow_in;
            int c = (pchunk & 24) | ((pchunk ^ row) & 7);
            gld16(pbuf + win * 1024, psrc + (size_t)row * CIN + c * 8);
        }
        #pragma unroll
        for (int i = 0; i < 4; ++i) {
            int win = w * 4 + i;
            int o = win * 16 + grow_in;
            int c = (gslot ^ o) & 3;
            gld16(gbuf + win * 1024, gTb + (size_t)o * NSP + it * 32 + c * 8);
        }
    };

    stage(0, 0);
    __syncthreads();

    for (int it = 0; it < 64; ++it) {
        int cur = it & 1;
        if (it < 63) stage(it + 1, cur ^ 1);   // drains at end-of-iter barrier
        const f16* phi_l = (const f16*)(smem + cur * 16384);
        const f16* g_l   = (const f16*)(smem + 32768 + cur * 16384);

        // S^T = phi_tile . theta^T : thread holds S[row=l15][m=16to+4q+r]
        f32x4 sT[2];
        sT[0] = (f32x4){0.f, 0.f, 0.f, 0.f};
        sT[1] = (f32x4){0.f, 0.f, 0.f, 0.f};
        #pragma unroll
        for (int kk = 0; kk < 8; ++kk) {
            int c = kk * 4 + q;
            int pos = (c & 24) | ((c ^ (l15 & 7)) & 7);
            #pragma unroll
            for (int to = 0; to < 2; ++to) {
                f16x8 af = *(const f16x8*)(phi_l + (16 * to + l15) * 256 + pos * 8);
                sT[to] = __builtin_amdgcn_mfma_f32_16x16x32_f16(af, th[kk], sT[to], 0, 0, 0);
            }
        }

        // online softmax: row l15 lives on this thread (8 vals) + 3 q-peers
        float tm = fmaxf(
            fmaxf(fmaxf(sT[0][0], sT[0][1]), fmaxf(sT[0][2], sT[0][3])),
            fmaxf(fmaxf(sT[1][0], sT[1][1]), fmaxf(sT[1][2], sT[1][3])));
        tm = fmaxf(tm, __shfl_xor(tm, 16));
        tm = fmaxf(tm, __shfl_xor(tm, 32));
        float mnew  = fmaxf(m_run, tm);
        float alpha = __expf(m_run - mnew);
        float rs = 0.f;
        #pragma unroll
        for (int to = 0; to < 2; ++to)
            #pragma unroll
            for (int r = 0; r < 4; ++r) {
                float p = __expf(sT[to][r] - mnew);
                sT[to][r] = p;
                rs += p;
            }
        rs += __shfl_xor(rs, 16);
        rs += __shfl_xor(rs, 32);
        l_run = l_run * alpha + rs;
        m_run = mnew;

        // P -> p_lds (wave-private rows; same-wave readback, lgkm only)
        #pragma unroll
        for (int to = 0; to < 2; ++to)
            #pragma unroll
            for (int r = 0; r < 4; ++r)
                p_lds[(16 * w + l15) * 40 + 16 * to + 4 * q + r] = (f16)sT[to][r];

        // rescale yacc rows (row of yacc[*][r] is q-row 4q+r)
        #pragma unroll
        for (int r = 0; r < 4; ++r) {
            float ar = __shfl(alpha, (lane & 48) | (4 * q + r));
            if (ar != 1.0f) {
                #pragma unroll
                for (int tco = 0; tco < 16; ++tco) yacc[tco][r] *= ar;
            }
        }

        // PV: A = P (k = m 0..31), B = g tile
        f16x8 pa = *(const f16x8*)(p_lds + (16 * w + l15) * 40 + q * 8);
        int gpos = (q ^ (l15 & 3)) & 3;
        #pragma unroll
        for (int tco = 0; tco < 16; ++tco) {
            f16x8 gfr = *(const f16x8*)(g_l + (16 * tco + l15) * 32 + gpos * 8);
            yacc[tco] = __builtin_amdgcn_mfma_f32_16x16x32_f16(pa, gfr, yacc[tco], 0, 0, 0);
        }

        __syncthreads();   // readers done + prefetch drained
    }

    // epilogue: y = yacc / l, staged through smem base (plain [64][256])
    float linv = 1.0f / l_run;   // for q-row l15
    f16* e_lds = (f16*)smem;
    #pragma unroll
    for (int r = 0; r < 4; ++r) {
        float iv = __shfl(linv, (lane & 48) | (4 * q + r));
        #pragma unroll
        for (int tco = 0; tco < 16; ++tco)
            e_lds[(16 * w + 4 * q + r) * 256 + 16 * tco + l15] =
                (f16)(yacc[tco][r] * iv);
    }
    __syncthreads();
    f16* dst = y + ((size_t)b * NSP + n0) * CIN;
    for (int k2 = 0; k2 < 8; ++k2) {
        int id = t + 256 * k2;
        *(f16x8*)(dst + id * 8) = *(const f16x8*)(e_lds + id * 8);
    }
}

// ---------------------------------------------------------------------------
// K3: Z = w_w . y^T, fused BN + residual. grid (N/64, C/64, B).
// ---------------------------------------------------------------------------
__global__ __launch_bounds__(256, 4) void k_out(
    const f16* __restrict__ yv, const f16* __restrict__ ww,
    const float* __restrict__ inv, const float* __restrict__ off,
    const float* __restrict__ x, float* __restrict__ out)
{
    __shared__ char smem[33792];            // union: y_lds f16[64*264] | z_lds f32[64*68]
    f16*   y_lds = (f16*)smem;
    float* z_lds = (float*)smem;
    int t = threadIdx.x;
    int w = t >> 6, lane = t & 63, l15 = lane & 15, q = lane >> 4;
    int n0 = blockIdx.x * 64, c0 = blockIdx.y * 64, b = blockIdx.z;

    const f16* src = yv + ((size_t)b * NSP + n0) * CIN;
    for (int k2 = 0; k2 < 8; ++k2) {
        int id = t + 256 * k2;
        int n = id >> 5, cc = id & 31;
        *(f16x8*)(y_lds + n * 264 + cc * 8) = *(const f16x8*)(src + id * 8);
    }
    __syncthreads();

    f32x4 acc[4];
    #pragma unroll
    for (int i = 0; i < 4; ++i) acc[i] = (f32x4){0.f, 0.f, 0.f, 0.f};
    const f16* wp = ww + (size_t)c0 * CIN + q * 8;
    #pragma unroll
    for (int kk = 0; kk < 8; ++kk) {
        f16x8 bfr = *(const f16x8*)(y_lds + (16 * w + l15) * 264 + kk * 32 + q * 8);
        #pragma unroll
        for (int tc = 0; tc < 4; ++tc) {
            f16x8 af = *(const f16x8*)(wp + (size_t)(16 * tc + l15) * CIN + kk * 32);
            acc[tc] = __builtin_amdgcn_mfma_f32_16x16x32_f16(af, bfr, acc[tc], 0, 0, 0);
        }
    }

    __syncthreads();   // y_lds reads done; reuse smem as f32 z tile

    #pragma unroll
    for (int tc = 0; tc < 4; ++tc)
        #pragma unroll
        for (int r = 0; r < 4; ++r)
            z_lds[(16 * tc + 4 * q + r) * 68 + 16 * w + l15] = acc[tc][r];
    __syncthreads();

    #pragma unroll
    for (int k2 = 0; k2 < 4; ++k2) {
        int f  = t + 256 * k2;
        int cl = f >> 4, n4 = f & 15;
        int c  = c0 + cl;
        float4 z = *(const float4*)(z_lds + cl * 68 + n4 * 4);
        size_t idx = ((size_t)b * CH + c) * NSP + n0 + n4 * 4;
        float4 xv = *(const float4*)(x + idx);
        float iv = inv[c], ov = off[c];
        float4 o;
        o.x = z.x * iv + ov + xv.x;
        o.y = z.y * iv + ov + xv.y;
        o.z = z.z * iv + ov + xv.z;
        o.w = z.w * iv + ov + xv.w;
        *(float4*)(out + idx) = o;
    }
}

// ---------------------------------------------------------------------------
extern "C" void kernel_launch(void* const* d_in, const int* in_sizes, int n_in,
                              void* d_out, int out_size, void* d_ws, size_t ws_size,
                              hipStream_t stream)
{
    const float* x     = (const float*)d_in[0];
    const float* tw    = (const float*)d_in[1];
    const float* tb    = (const float*)d_in[2];
    const float* pw    = (const float*)d_in[3];
    const float* pb    = (const float*)d_in[4];
    const float* gw    = (const float*)d_in[5];
    const float* gb_   = (const float*)d_in[6];
    const float* ww    = (const float*)d_in[7];
    const float* wb    = (const float*)d_in[8];
    const float* gamma = (const float*)d_in[9];
    const float* beta  = (const float*)d_in[10];
    const float* mean  = (const float*)d_in[11];
    const float* var   = (const float*)d_in[12];
    float* out = (float*)d_out;

    char* ws = (char*)d_ws;
    f16* xT    = (f16*)ws;                    //  67108864 B
    f16* theta = (f16*)(ws + 67108864);       //  16777216 B
    f16* phiT  = (f16*)(ws + 83886080);       //  16777216 B
    f16* gT    = (f16*)(ws + 100663296);      //  16777216 B
    f16* yv    = (f16*)(ws + 117440512);      //  16777216 B
    f16* w_all = (f16*)(ws + 134217728);      //  4*524288 B
    float* inv  = (float*)(ws + 136314880);   //  4096 B
    float* offv = (float*)(ws + 136318976);   //  4096 B

    k_prep<<<4100, 256, 0, stream>>>(tw, pw, gw, ww, wb, gamma, beta, mean, var,
                                     w_all, inv, offv);
    k_transpose_x<<<dim3(32, 16, 16), 256, 0, stream>>>(x, xT);
    k_qkv<<<dim3(32, 16, 3), 256, 0, stream>>>(xT, w_all, tb, pb, gb_, theta, phiT, gT);
    k_attn<<<dim3(32, 16), 256, 0, stream>>>(theta, phiT, gT, yv);
    k_out<<<dim3(32, 16, 16), 256, 0, stream>>>(yv, w_all + 3 * 262144, inv, offv, x, out);
}

// Round 3
// 483.806 us; speedup vs baseline: 1.2067x; 1.1576x over previous
//
#include <hip/hip_runtime.h>
#include <cstdint>

#define BATCH 16
#define CH 1024
#define CIN 256
#define NSP 2048   // H*W = 64*32
#define BN_EPS 1e-5f

typedef _Float16 f16;
typedef f16   f16x8 __attribute__((ext_vector_type(8)));
typedef float f32x4 __attribute__((ext_vector_type(4)));

typedef __attribute__((address_space(3))) void lds_t;
typedef __attribute__((address_space(1))) const void gbl_t;

// async 16B/lane global->LDS (LDS dest = wave-uniform base + lane*16)
__device__ __forceinline__ void gld16(void* l, const void* g) {
    __builtin_amdgcn_global_load_lds((gbl_t*)g, (lds_t*)l, 16, 0, 0);
}

// ---------------------------------------------------------------------------
// P0: weights -> fp16; fold BN+bias into inv/off
// ---------------------------------------------------------------------------
__global__ __launch_bounds__(256) void k_prep(
    const float* __restrict__ tw, const float* __restrict__ pw,
    const float* __restrict__ gw, const float* __restrict__ ww,
    const float* __restrict__ wb, const float* __restrict__ gamma,
    const float* __restrict__ beta, const float* __restrict__ mean,
    const float* __restrict__ var,
    f16* __restrict__ w_all, float* __restrict__ inv_out, float* __restrict__ off_out)
{
    int id = blockIdx.x * 256 + threadIdx.x;
    if (id < 4 * 262144) {
        int sel = id >> 18, off = id & 262143;
        const float* src = sel == 0 ? tw : sel == 1 ? pw : sel == 2 ? gw : ww;
        w_all[id] = (f16)src[off];
    } else {
        int c = id - 4 * 262144;
        if (c < CH) {
            float iv = gamma[c] * rsqrtf(var[c] + BN_EPS);
            inv_out[c] = iv;
            off_out[c] = (wb[c] - mean[c]) * iv + beta[c];
        }
    }
}

// ---------------------------------------------------------------------------
// P1: x [B,C,N] fp32 -> xT [B,N,C] fp16
// ---------------------------------------------------------------------------
__global__ __launch_bounds__(256) void k_transpose_x(
    const float* __restrict__ x, f16* __restrict__ xT)
{
    __shared__ float tile[64 * 65];
    int t = threadIdx.x;
    int n0 = blockIdx.x * 64, c0 = blockIdx.y * 64, b = blockIdx.z;
    const float* xb = x + (size_t)b * CH * NSP;
    for (int k = 0; k < 4; ++k) {
        int id = t + 256 * k;
        int row = id >> 4, cc = id & 15;
        float4 v = *(const float4*)(xb + (size_t)(c0 + row) * NSP + n0 + cc * 4);
        tile[row * 65 + cc * 4 + 0] = v.x;
        tile[row * 65 + cc * 4 + 1] = v.y;
        tile[row * 65 + cc * 4 + 2] = v.z;
        tile[row * 65 + cc * 4 + 3] = v.w;
    }
    __syncthreads();
    f16* xTb = xT + (size_t)b * NSP * CH;
    for (int k = 0; k < 2; ++k) {
        int id = t + 256 * k;
        int n = id >> 3, c8 = id & 7;
        f16x8 o;
        #pragma unroll
        for (int j = 0; j < 8; ++j) o[j] = (f16)tile[(c8 * 8 + j) * 65 + n];
        *(f16x8*)(xTb + (size_t)(n0 + n) * CH + c0 + c8 * 8) = o;
    }
}

// ---------------------------------------------------------------------------
// K1: QKV projections, m97-style: BK=64, global_load_lds(16B) staging into
// XOR-swizzled unpadded LDS tiles. grid (N/64, B, 3); tile 64n x 256o.
// ---------------------------------------------------------------------------
__global__ __launch_bounds__(256, 3) void k_qkv(
    const f16* __restrict__ xT, const f16* __restrict__ w_all,
    const float* __restrict__ tb, const float* __restrict__ pb,
    const float* __restrict__ gb,
    f16* __restrict__ theta, f16* __restrict__ phiT, f16* __restrict__ gT)
{
    __shared__ char smem[40960];
    f16* a_lds = (f16*)smem;            // [64][64]  swizzled (8 KB)
    f16* b_lds = (f16*)(smem + 8192);   // [256][64] swizzled (32 KB)
    int t = threadIdx.x;
    int w = t >> 6, lane = t & 63, l15 = lane & 15, q = lane >> 4;
    int sw = l15 & 7;
    int n0 = blockIdx.x * 64, b = blockIdx.y, set = blockIdx.z;
    const f16* W  = w_all + (size_t)set * (CIN * CH);
    const f16* xA = xT + ((size_t)b * NSP + n0) * CH;

    int rA  = lane >> 3;             // row-in-window 0..7
    int ccs = (lane & 7) ^ rA;       // swizzled global chunk for this lane

    f32x4 acc[4][4];
    #pragma unroll
    for (int i = 0; i < 4; ++i)
        #pragma unroll
        for (int j = 0; j < 4; ++j) acc[i][j] = (f32x4){0.f, 0.f, 0.f, 0.f};

    for (int it = 0; it < 16; ++it) {
        #pragma unroll
        for (int i = 0; i < 2; ++i) {
            int win = w * 2 + i;
            int n = win * 8 + rA;
            gld16((char*)a_lds + win * 1024,
                  xA + (size_t)n * CH + it * 64 + ccs * 8);
        }
        #pragma unroll
        for (int i = 0; i < 8; ++i) {
            int win = w * 8 + i;
            int o = win * 8 + rA;
            gld16((char*)b_lds + win * 1024,
                  W + (size_t)o * CH + it * 64 + ccs * 8);
        }
        __syncthreads();

        #pragma unroll
        for (int kl = 0; kl < 2; ++kl) {
            int c16 = kl * 4 + q;
            int pos = (c16 ^ sw) & 7;
            f16x8 af[4], bfr[4];
            #pragma unroll
            for (int tn = 0; tn < 4; ++tn)
                af[tn] = *(const f16x8*)(a_lds + (16 * tn + l15) * 64 + pos * 8);
            #pragma unroll
            for (int to = 0; to < 4; ++to)
                bfr[to] = *(const f16x8*)(b_lds + (64 * w + 16 * to + l15) * 64 + pos * 8);
            #pragma unroll
            for (int tn = 0; tn < 4; ++tn)
                #pragma unroll
                for (int to = 0; to < 4; ++to)
                    acc[tn][to] = __builtin_amdgcn_mfma_f32_16x16x32_f16(
                        af[tn], bfr[to], acc[tn][to], 0, 0, 0);
        }
        __syncthreads();
    }

    const float* bias = set == 0 ? tb : set == 1 ? pb : gb;
    float bv[4];
    #pragma unroll
    for (int to = 0; to < 4; ++to) bv[to] = bias[64 * w + 16 * to + l15];

    if (set < 2) {
        f16* e_lds = (f16*)smem;  // [64][256]
        #pragma unroll
        for (int tn = 0; tn < 4; ++tn)
            #pragma unroll
            for (int to = 0; to < 4; ++to)
                #pragma unroll
                for (int r = 0; r < 4; ++r)
                    e_lds[(16 * tn + 4 * q + r) * 256 + 64 * w + 16 * to + l15] =
                        (f16)(acc[tn][to][r] + bv[to]);
        __syncthreads();
        f16* dst = (set == 0 ? theta : phiT) + ((size_t)b * NSP + n0) * CIN;
        for (int k2 = 0; k2 < 8; ++k2) {
            int id = t + 256 * k2;
            *(f16x8*)(dst + id * 8) = *(const f16x8*)(e_lds + id * 8);
        }
    } else {
        f16* e_lds = (f16*)smem;  // [256][72]
        #pragma unroll
        for (int tn = 0; tn < 4; ++tn)
            #pragma unroll
            for (int to = 0; to < 4; ++to)
                #pragma unroll
                for (int r = 0; r < 4; ++r)
                    e_lds[(64 * w + 16 * to + l15) * 72 + 16 * tn + 4 * q + r] =
                        (f16)(acc[tn][to][r] + bv[to]);
        __syncthreads();
        f16* dst = gT + (size_t)b * CIN * NSP + n0;
        for (int k2 = 0; k2 < 8; ++k2) {
            int id = t + 256 * k2;
            int o = id >> 3, cc = id & 7;
            *(f16x8*)(dst + (size_t)o * NSP + cc * 8) = *(const f16x8*)(e_lds + o * 72 + cc * 8);
        }
    }
}

// ---------------------------------------------------------------------------
// K2: flash attention v3. KVBLK=32, async gld16 double-buffered staging,
// swapped QK^T (S^T via A=phi, B=theta-in-regs) -> in-thread softmax with
// 2 shfl_xor rounds; ONE barrier per iteration. grid (N/64, B).
// LDS: phi dbuf 2x16K [32][256] swz | g dbuf 2x16K [256][32] swz | p 5K.
// ---------------------------------------------------------------------------
__global__ __launch_bounds__(256, 2) void k_attn(
    const f16* __restrict__ theta, const f16* __restrict__ phiT,
    const f16* __restrict__ gT, f16* __restrict__ y)
{
    __shared__ char smem[70656];
    f16* p_lds = (f16*)(smem + 65536);       // [64][40]
    int t = threadIdx.x;
    int w = t >> 6, lane = t & 63, l15 = lane & 15, q = lane >> 4;
    int n0 = blockIdx.x * 64, b = blockIdx.y;

    // theta in regs: valid directly as the MFMA B-operand (col = l15 = q-row)
    f16x8 th[8];
    const f16* thp = theta + ((size_t)b * NSP + n0 + 16 * w + l15) * CIN + q * 8;
    #pragma unroll
    for (int kk = 0; kk < 8; ++kk) th[kk] = *(const f16x8*)(thp + kk * 32);

    f32x4 yacc[16];
    #pragma unroll
    for (int i = 0; i < 16; ++i) yacc[i] = (f32x4){0.f, 0.f, 0.f, 0.f};
    float m_run = -INFINITY, l_run = 0.f;

    const f16* phib = phiT + (size_t)b * NSP * CIN;
    const f16* gTb  = gT + (size_t)b * CIN * NSP;

    // staging lane decomposition
    int prow_in = lane >> 5;   // phi: row within 2-row window
    int pchunk  = lane & 31;   // phi: 16B slot within 512B row
    int grow_in = lane >> 2;   // g: o-row within 16-row window
    int gslot   = lane & 3;    // g: 16B slot within 64B row

    auto stage = [&](int it, int bufsel) {
        char* pbuf = smem + bufsel * 16384;
        char* gbuf = smem + 32768 + bufsel * 16384;
        const f16* psrc = phib + (size_t)(it * 32) * CIN;
        #pragma unroll
        for (int i = 0; i < 4; ++i) {
            int win = w * 4 + i;
            int row = win * 2 + prow_in;
            int c = (pchunk & 24) | ((pchunk ^ row) & 7);
            gld16(pbuf + win * 1024, psrc + (size_t)row * CIN + c * 8);
        }
        #pragma unroll
        for (int i = 0; i < 4; ++i) {
            int win = w * 4 + i;
            int o = win * 16 + grow_in;
            int c = (gslot ^ o) & 3;
            gld16(gbuf + win * 1024, gTb + (size_t)o * NSP + it * 32 + c * 8);
        }
    };

    stage(0, 0);
    __syncthreads();

    for (int it = 0; it < 64; ++it) {
        int cur = it & 1;
        if (it < 63) stage(it + 1, cur ^ 1);   // drains at end-of-iter barrier
        const f16* phi_l = (const f16*)(smem + cur * 16384);
        const f16* g_l   = (const f16*)(smem + 32768 + cur * 16384);

        // S^T = phi_tile . theta^T : thread holds S[row=l15][m=16to+4q+r]
        f32x4 sT[2];
        sT[0] = (f32x4){0.f, 0.f, 0.f, 0.f};
        sT[1] = (f32x4){0.f, 0.f, 0.f, 0.f};
        #pragma unroll
        for (int kk = 0; kk < 8; ++kk) {
            int c = kk * 4 + q;
            int pos = (c & 24) | ((c ^ (l15 & 7)) & 7);
            #pragma unroll
            for (int to = 0; to < 2; ++to) {
                f16x8 af = *(const f16x8*)(phi_l + (16 * to + l15) * 256 + pos * 8);
                sT[to] = __builtin_amdgcn_mfma_f32_16x16x32_f16(af, th[kk], sT[to], 0, 0, 0);
            }
        }

        // online softmax: row l15 lives on this thread (8 vals) + 3 q-peers
        float tm = fmaxf(
            fmaxf(fmaxf(sT[0][0], sT[0][1]), fmaxf(sT[0][2], sT[0][3])),
            fmaxf(fmaxf(sT[1][0], sT[1][1]), fmaxf(sT[1][2], sT[1][3])));
        tm = fmaxf(tm, __shfl_xor(tm, 16));
        tm = fmaxf(tm, __shfl_xor(tm, 32));
        float mnew  = fmaxf(m_run, tm);
        float alpha = __expf(m_run - mnew);
        float rs = 0.f;
        #pragma unroll
        for (int to = 0; to < 2; ++to)
            #pragma unroll
            for (int r = 0; r < 4; ++r) {
                float p = __expf(sT[to][r] - mnew);
                sT[to][r] = p;
                rs += p;
            }
        rs += __shfl_xor(rs, 16);
        rs += __shfl_xor(rs, 32);
        l_run = l_run * alpha + rs;
        m_run = mnew;

        // P -> p_lds (wave-private rows; same-wave readback, lgkm only)
        #pragma unroll
        for (int to = 0; to < 2; ++to)
            #pragma unroll
            for (int r = 0; r < 4; ++r)
                p_lds[(16 * w + l15) * 40 + 16 * to + 4 * q + r] = (f16)sT[to][r];

        // rescale yacc rows (row of yacc[*][r] is q-row 4q+r)
        #pragma unroll
        for (int r = 0; r < 4; ++r) {
            float ar = __shfl(alpha, (lane & 48) | (4 * q + r));
            if (ar != 1.0f) {
                #pragma unroll
                for (int tco = 0; tco < 16; ++tco) yacc[tco][r] *= ar;
            }
        }

        // PV: A = P (k = m 0..31), B = g tile
        f16x8 pa = *(const f16x8*)(p_lds + (16 * w + l15) * 40 + q * 8);
        int gpos = (q ^ (l15 & 3)) & 3;
        #pragma unroll
        for (int tco = 0; tco < 16; ++tco) {
            f16x8 gfr = *(const f16x8*)(g_l + (16 * tco + l15) * 32 + gpos * 8);
            yacc[tco] = __builtin_amdgcn_mfma_f32_16x16x32_f16(pa, gfr, yacc[tco], 0, 0, 0);
        }

        __syncthreads();   // readers done + prefetch drained
    }

    // epilogue: y = yacc / l, staged through smem base (plain [64][256])
    float linv = 1.0f / l_run;   // for q-row l15
    f16* e_lds = (f16*)smem;
    #pragma unroll
    for (int r = 0; r < 4; ++r) {
        float iv = __shfl(linv, (lane & 48) | (4 * q + r));
        #pragma unroll
        for (int tco = 0; tco < 16; ++tco)
            e_lds[(16 * w + 4 * q + r) * 256 + 16 * tco + l15] =
                (f16)(yacc[tco][r] * iv);
    }
    __syncthreads();
    f16* dst = y + ((size_t)b * NSP + n0) * CIN;
    for (int k2 = 0; k2 < 8; ++k2) {
        int id = t + 256 * k2;
        *(f16x8*)(dst + id * 8) = *(const f16x8*)(e_lds + id * 8);
    }
}

// ---------------------------------------------------------------------------
// K3: Z = w_w . y^T + BN + residual, rebuilt as the k_qkv m97 structure.
// Tile 64n x 256c, K=CIN=256 in 4 BK=64 steps, gld16 -> swizzled LDS for
// BOTH operands. grid (N/64, C/256, B) = (32,4,16). Epilogue: 4 c-slabs
// bounced via f32 z_lds [64][68] (aliased), coalesced float4 x/out, with
// next-slab x prefetch.
// ---------------------------------------------------------------------------
__global__ __launch_bounds__(256, 3) void k_out(
    const f16* __restrict__ yv, const f16* __restrict__ ww,
    const float* __restrict__ inv, const float* __restrict__ off,
    const float* __restrict__ x, float* __restrict__ out)
{
    __shared__ char smem[40960];
    f16*   a_lds = (f16*)smem;            // [64][64]  y tile, swizzled (8 KB)
    f16*   b_lds = (f16*)(smem + 8192);   // [256][64] w tile, swizzled (32 KB)
    float* z_lds = (float*)smem;          // [64][68] f32 bounce (17.4 KB, alias)
    int t = threadIdx.x;
    int w = t >> 6, lane = t & 63, l15 = lane & 15, q = lane >> 4;
    int sw = l15 & 7;
    int n0 = blockIdx.x * 64, cb = blockIdx.y * 256, b = blockIdx.z;

    const f16* yA = yv + ((size_t)b * NSP + n0) * CIN;
    const f16* W  = ww + (size_t)cb * CIN;

    int rA  = lane >> 3;             // row-in-window 0..7
    int ccs = (lane & 7) ^ rA;       // swizzled global chunk for this lane

    f32x4 acc[4][4];
    #pragma unroll
    for (int i = 0; i < 4; ++i)
        #pragma unroll
        for (int j = 0; j < 4; ++j) acc[i][j] = (f32x4){0.f, 0.f, 0.f, 0.f};

    for (int it = 0; it < 4; ++it) {
        #pragma unroll
        for (int i = 0; i < 2; ++i) {
            int win = w * 2 + i;
            int n = win * 8 + rA;
            gld16((char*)a_lds + win * 1024,
                  yA + (size_t)n * CIN + it * 64 + ccs * 8);
        }
        #pragma unroll
        for (int i = 0; i < 8; ++i) {
            int win = w * 8 + i;
            int o = win * 8 + rA;
            gld16((char*)b_lds + win * 1024,
                  W + (size_t)o * CIN + it * 64 + ccs * 8);
        }
        __syncthreads();

        #pragma unroll
        for (int kl = 0; kl < 2; ++kl) {
            int c16 = kl * 4 + q;
            int pos = (c16 ^ sw) & 7;
            f16x8 af[4], bfr[4];
            #pragma unroll
            for (int tn = 0; tn < 4; ++tn)
                af[tn] = *(const f16x8*)(a_lds + (16 * tn + l15) * 64 + pos * 8);
            #pragma unroll
            for (int to = 0; to < 4; ++to)
                bfr[to] = *(const f16x8*)(b_lds + (64 * w + 16 * to + l15) * 64 + pos * 8);
            #pragma unroll
            for (int tn = 0; tn < 4; ++tn)
                #pragma unroll
                for (int to = 0; to < 4; ++to)
                    acc[tn][to] = __builtin_amdgcn_mfma_f32_16x16x32_f16(
                        af[tn], bfr[to], acc[tn][to], 0, 0, 0);
        }
        __syncthreads();
    }

    // ---- epilogue: 4 slabs over `to` (c-fragment); z bounce for coalescing.
    // acc[tn][to][r] lives at (n_local = 16tn+4q+r, c = cb + 64w + 16to + l15).
    // Slab row zr = 16w + l15 -> c = cb + 64*(zr>>4) + 16*to + (zr&15).
    float4 xv[4];
    #pragma unroll
    for (int k2 = 0; k2 < 4; ++k2) {
        int f = t + 256 * k2;
        int zrr = f >> 4, nn4 = f & 15;
        int c = cb + 64 * (zrr >> 4) + (zrr & 15);   // to = 0
        xv[k2] = *(const float4*)(x + ((size_t)b * CH + c) * NSP + n0 + nn4 * 4);
    }

    #pragma unroll
    for (int to = 0; to < 4; ++to) {
        #pragma unroll
        for (int tn = 0; tn < 4; ++tn)
            #pragma unroll
            for (int r = 0; r < 4; ++r)
                z_lds[(16 * w + l15) * 68 + 16 * tn + 4 * q + r] = acc[tn][to][r];
        __syncthreads();

        float4 nxt[4];
        if (to < 3) {
            #pragma unroll
            for (int k2 = 0; k2 < 4; ++k2) {
                int f = t + 256 * k2;
                int zrr = f >> 4, nn4 = f & 15;
                int c = cb + 64 * (zrr >> 4) + 16 * (to + 1) + (zrr & 15);
                nxt[k2] = *(const float4*)(x + ((size_t)b * CH + c) * NSP + n0 + nn4 * 4);
            }
        }

        #pragma unroll
        for (int k2 = 0; k2 < 4; ++k2) {
            int f = t + 256 * k2;
            int zrr = f >> 4, nn4 = f & 15;
            int c = cb + 64 * (zrr >> 4) + 16 * to + (zrr & 15);
            float4 z = *(const float4*)(z_lds + zrr * 68 + nn4 * 4);
            float iv = inv[c], ov = off[c];
            size_t idx = ((size_t)b * CH + c) * NSP + n0 + nn4 * 4;
            float4 o;
            o.x = z.x * iv + ov + xv[k2].x;
            o.y = z.y * iv + ov + xv[k2].y;
            o.z = z.z * iv + ov + xv[k2].z;
            o.w = z.w * iv + ov + xv[k2].w;
            *(float4*)(out + idx) = o;
        }

        if (to < 3) {
            #pragma unroll
            for (int k2 = 0; k2 < 4; ++k2) xv[k2] = nxt[k2];
            __syncthreads();   // z reads done before next slab's writes
        }
    }
}

// ---------------------------------------------------------------------------
extern "C" void kernel_launch(void* const* d_in, const int* in_sizes, int n_in,
                              void* d_out, int out_size, void* d_ws, size_t ws_size,
                              hipStream_t stream)
{
    const float* x     = (const float*)d_in[0];
    const float* tw    = (const float*)d_in[1];
    const float* tb    = (const float*)d_in[2];
    const float* pw    = (const float*)d_in[3];
    const float* pb    = (const float*)d_in[4];
    const float* gw    = (const float*)d_in[5];
    const float* gb_   = (const float*)d_in[6];
    const float* ww    = (const float*)d_in[7];
    const float* wb    = (const float*)d_in[8];
    const float* gamma = (const float*)d_in[9];
    const float* beta  = (const float*)d_in[10];
    const float* mean  = (const float*)d_in[11];
    const float* var   = (const float*)d_in[12];
    float* out = (float*)d_out;

    char* ws = (char*)d_ws;
    f16* xT    = (f16*)ws;                    //  67108864 B
    f16* theta = (f16*)(ws + 67108864);       //  16777216 B
    f16* phiT  = (f16*)(ws + 83886080);       //  16777216 B
    f16* gT    = (f16*)(ws + 100663296);      //  16777216 B
    f16* yv    = (f16*)(ws + 117440512);      //  16777216 B
    f16* w_all = (f16*)(ws + 134217728);      //  4*524288 B
    float* inv  = (float*)(ws + 136314880);   //  4096 B
    float* offv = (float*)(ws + 136318976);   //  4096 B

    k_prep<<<4100, 256, 0, stream>>>(tw, pw, gw, ww, wb, gamma, beta, mean, var,
                                     w_all, inv, offv);
    k_transpose_x<<<dim3(32, 16, 16), 256, 0, stream>>>(x, xT);
    k_qkv<<<dim3(32, 16, 3), 256, 0, stream>>>(xT, w_all, tb, pb, gb_, theta, phiT, gT);
    k_attn<<<dim3(32, 16), 256, 0, stream>>>(theta, phiT, gT, yv);
    k_out<<<dim3(32, 4, 16), 256, 0, stream>>>(yv, w_all + 3 * 262144, inv, offv, x, out);
}

// Round 4
// 479.743 us; speedup vs baseline: 1.2169x; 1.0085x over previous
//
#include <hip/hip_runtime.h>
#include <cstdint>

#define BATCH 16
#define CH 1024
#define CIN 256
#define NSP 2048   // H*W = 64*32
#define BN_EPS 1e-5f

typedef _Float16 f16;
typedef f16   f16x4 __attribute__((ext_vector_type(4)));
typedef f16   f16x8 __attribute__((ext_vector_type(8)));
typedef float f32x4 __attribute__((ext_vector_type(4)));

typedef __attribute__((address_space(3))) void lds_t;
typedef __attribute__((address_space(1))) const void gbl_t;

// async 16B/lane global->LDS (LDS dest = wave-uniform base + lane*16)
__device__ __forceinline__ void gld16(void* l, const void* g) {
    __builtin_amdgcn_global_load_lds((gbl_t*)g, (lds_t*)l, 16, 0, 0);
}

// ---------------------------------------------------------------------------
// P0: weights -> fp16; fold BN+bias into inv/off
// ---------------------------------------------------------------------------
__global__ __launch_bounds__(256) void k_prep(
    const float* __restrict__ tw, const float* __restrict__ pw,
    const float* __restrict__ gw, const float* __restrict__ ww,
    const float* __restrict__ wb, const float* __restrict__ gamma,
    const float* __restrict__ beta, const float* __restrict__ mean,
    const float* __restrict__ var,
    f16* __restrict__ w_all, float* __restrict__ inv_out, float* __restrict__ off_out)
{
    int id = blockIdx.x * 256 + threadIdx.x;
    if (id < 4 * 262144) {
        int sel = id >> 18, off = id & 262143;
        const float* src = sel == 0 ? tw : sel == 1 ? pw : sel == 2 ? gw : ww;
        w_all[id] = (f16)src[off];
    } else {
        int c = id - 4 * 262144;
        if (c < CH) {
            float iv = gamma[c] * rsqrtf(var[c] + BN_EPS);
            inv_out[c] = iv;
            off_out[c] = (wb[c] - mean[c]) * iv + beta[c];
        }
    }
}

// ---------------------------------------------------------------------------
// P1: x [B,C,N] fp32 -> xT [B,N,C] fp16
// ---------------------------------------------------------------------------
__global__ __launch_bounds__(256) void k_transpose_x(
    const float* __restrict__ x, f16* __restrict__ xT)
{
    __shared__ float tile[64 * 65];
    int t = threadIdx.x;
    int n0 = blockIdx.x * 64, c0 = blockIdx.y * 64, b = blockIdx.z;
    const float* xb = x + (size_t)b * CH * NSP;
    for (int k = 0; k < 4; ++k) {
        int id = t + 256 * k;
        int row = id >> 4, cc = id & 15;
        float4 v = *(const float4*)(xb + (size_t)(c0 + row) * NSP + n0 + cc * 4);
        tile[row * 65 + cc * 4 + 0] = v.x;
        tile[row * 65 + cc * 4 + 1] = v.y;
        tile[row * 65 + cc * 4 + 2] = v.z;
        tile[row * 65 + cc * 4 + 3] = v.w;
    }
    __syncthreads();
    f16* xTb = xT + (size_t)b * NSP * CH;
    for (int k = 0; k < 2; ++k) {
        int id = t + 256 * k;
        int n = id >> 3, c8 = id & 7;
        f16x8 o;
        #pragma unroll
        for (int j = 0; j < 8; ++j) o[j] = (f16)tile[(c8 * 8 + j) * 65 + n];
        *(f16x8*)(xTb + (size_t)(n0 + n) * CH + c0 + c8 * 8) = o;
    }
}

// ---------------------------------------------------------------------------
// K1: QKV projections, m97-style: BK=64, global_load_lds(16B) staging into
// XOR-swizzled unpadded LDS tiles. grid (N/64, B, 3); tile 64n x 256o.
// ---------------------------------------------------------------------------
__global__ __launch_bounds__(256, 3) void k_qkv(
    const f16* __restrict__ xT, const f16* __restrict__ w_all,
    const float* __restrict__ tb, const float* __restrict__ pb,
    const float* __restrict__ gb,
    f16* __restrict__ theta, f16* __restrict__ phiT, f16* __restrict__ gT)
{
    __shared__ char smem[40960];
    f16* a_lds = (f16*)smem;            // [64][64]  swizzled (8 KB)
    f16* b_lds = (f16*)(smem + 8192);   // [256][64] swizzled (32 KB)
    int t = threadIdx.x;
    int w = t >> 6, lane = t & 63, l15 = lane & 15, q = lane >> 4;
    int sw = l15 & 7;
    int n0 = blockIdx.x * 64, b = blockIdx.y, set = blockIdx.z;
    const f16* W  = w_all + (size_t)set * (CIN * CH);
    const f16* xA = xT + ((size_t)b * NSP + n0) * CH;

    int rA  = lane >> 3;             // row-in-window 0..7
    int ccs = (lane & 7) ^ rA;       // swizzled global chunk for this lane

    f32x4 acc[4][4];
    #pragma unroll
    for (int i = 0; i < 4; ++i)
        #pragma unroll
        for (int j = 0; j < 4; ++j) acc[i][j] = (f32x4){0.f, 0.f, 0.f, 0.f};

    for (int it = 0; it < 16; ++it) {
        #pragma unroll
        for (int i = 0; i < 2; ++i) {
            int win = w * 2 + i;
            int n = win * 8 + rA;
            gld16((char*)a_lds + win * 1024,
                  xA + (size_t)n * CH + it * 64 + ccs * 8);
        }
        #pragma unroll
        for (int i = 0; i < 8; ++i) {
            int win = w * 8 + i;
            int o = win * 8 + rA;
            gld16((char*)b_lds + win * 1024,
                  W + (size_t)o * CH + it * 64 + ccs * 8);
        }
        __syncthreads();

        #pragma unroll
        for (int kl = 0; kl < 2; ++kl) {
            int c16 = kl * 4 + q;
            int pos = (c16 ^ sw) & 7;
            f16x8 af[4], bfr[4];
            #pragma unroll
            for (int tn = 0; tn < 4; ++tn)
                af[tn] = *(const f16x8*)(a_lds + (16 * tn + l15) * 64 + pos * 8);
            #pragma unroll
            for (int to = 0; to < 4; ++to)
                bfr[to] = *(const f16x8*)(b_lds + (64 * w + 16 * to + l15) * 64 + pos * 8);
            #pragma unroll
            for (int tn = 0; tn < 4; ++tn)
                #pragma unroll
                for (int to = 0; to < 4; ++to)
                    acc[tn][to] = __builtin_amdgcn_mfma_f32_16x16x32_f16(
                        af[tn], bfr[to], acc[tn][to], 0, 0, 0);
        }
        __syncthreads();
    }

    const float* bias = set == 0 ? tb : set == 1 ? pb : gb;
    float bv[4];
    #pragma unroll
    for (int to = 0; to < 4; ++to) bv[to] = bias[64 * w + 16 * to + l15];

    if (set < 2) {
        f16* e_lds = (f16*)smem;  // [64][256]
        #pragma unroll
        for (int tn = 0; tn < 4; ++tn)
            #pragma unroll
            for (int to = 0; to < 4; ++to)
                #pragma unroll
                for (int r = 0; r < 4; ++r)
                    e_lds[(16 * tn + 4 * q + r) * 256 + 64 * w + 16 * to + l15] =
                        (f16)(acc[tn][to][r] + bv[to]);
        __syncthreads();
        f16* dst = (set == 0 ? theta : phiT) + ((size_t)b * NSP + n0) * CIN;
        for (int k2 = 0; k2 < 8; ++k2) {
            int id = t + 256 * k2;
            *(f16x8*)(dst + id * 8) = *(const f16x8*)(e_lds + id * 8);
        }
    } else {
        f16* e_lds = (f16*)smem;  // [256][72]
        #pragma unroll
        for (int tn = 0; tn < 4; ++tn)
            #pragma unroll
            for (int to = 0; to < 4; ++to)
                #pragma unroll
                for (int r = 0; r < 4; ++r)
                    e_lds[(64 * w + 16 * to + l15) * 72 + 16 * tn + 4 * q + r] =
                        (f16)(acc[tn][to][r] + bv[to]);
        __syncthreads();
        f16* dst = gT + (size_t)b * CIN * NSP + n0;
        for (int k2 = 0; k2 < 8; ++k2) {
            int id = t + 256 * k2;
            int o = id >> 3, cc = id & 7;
            *(f16x8*)(dst + (size_t)o * NSP + cc * 8) = *(const f16x8*)(e_lds + o * 72 + cc * 8);
        }
    }
}

// ---------------------------------------------------------------------------
// K2: flash attention v4. KVBLK=32, phi via gld16 dbuf (swizzled [32][256]);
// g via T14 reg-staging into PADDED [256][40] (80B rows -> conflict-free
// ds_read_b128, no swizzle on read); P packed as 2x b64 writes into padded
// [64][40]. ONE barrier per iteration. grid (B, N/64): block-id = b mod 8
// pins each batch to one XCD -> L2-resident phi/g.
// LDS: phi 2x16K | g 2x20K | p 5K = 77 KB.
// ---------------------------------------------------------------------------
__global__ __launch_bounds__(256, 2) void k_attn(
    const f16* __restrict__ theta, const f16* __restrict__ phiT,
    const f16* __restrict__ gT, f16* __restrict__ y)
{
    __shared__ char smem[78848];
    f16* p_lds = (f16*)(smem + 73728);       // [64][40]
    int t = threadIdx.x;
    int w = t >> 6, lane = t & 63, l15 = lane & 15, q = lane >> 4;
    int b = blockIdx.x, n0 = blockIdx.y * 64;

    // theta in regs: valid directly as the MFMA B-operand (col = l15 = q-row)
    f16x8 th[8];
    const f16* thp = theta + ((size_t)b * NSP + n0 + 16 * w + l15) * CIN + q * 8;
    #pragma unroll
    for (int kk = 0; kk < 8; ++kk) th[kk] = *(const f16x8*)(thp + kk * 32);

    f32x4 yacc[16];
    #pragma unroll
    for (int i = 0; i < 16; ++i) yacc[i] = (f32x4){0.f, 0.f, 0.f, 0.f};
    float m_run = -INFINITY, l_run = 0.f;

    const f16* phib = phiT + (size_t)b * NSP * CIN;
    const f16* gTb  = gT + (size_t)b * CIN * NSP;

    // phi staging (async gld16, swizzled [32][256], dbuf)
    int prow_in = lane >> 5;   // row within 2-row window
    int pchunk  = lane & 31;   // 16B slot within 512B row
    auto stage_phi = [&](int it, int sel) {
        char* pbuf = smem + sel * 16384;
        const f16* psrc = phib + (size_t)(it * 32) * CIN;
        #pragma unroll
        for (int i = 0; i < 4; ++i) {
            int win = w * 4 + i;
            int row = win * 2 + prow_in;
            int c = (pchunk & 24) | ((pchunk ^ row) & 7);
            gld16(pbuf + win * 1024, psrc + (size_t)row * CIN + c * 8);
        }
    };

    // g reg staging: thread covers rows go+64i, k-chunk gc (padded [256][40])
    int go = t >> 2;           // base row 0..63
    int gc = t & 3;            // 16B k-chunk 0..3
    f16x8 gr[4];
    auto load_g = [&](int it) {
        #pragma unroll
        for (int i = 0; i < 4; ++i)
            gr[i] = *(const f16x8*)(gTb + (size_t)(i * 64 + go) * NSP + it * 32 + gc * 8);
    };
    auto write_g = [&](int sel) {
        f16* gb = (f16*)(smem + 32768 + sel * 20480);
        #pragma unroll
        for (int i = 0; i < 4; ++i)
            *(f16x8*)(gb + (i * 64 + go) * 40 + gc * 8) = gr[i];
    };

    // prologue: tile 0
    load_g(0);
    stage_phi(0, 0);
    write_g(0);
    __syncthreads();

    for (int it = 0; it < 64; ++it) {
        int cur = it & 1;
        // issue next-tile global loads early (latency hidden under S+softmax)
        if (it < 63) {
            load_g(it + 1);
            stage_phi(it + 1, cur ^ 1);   // phi[cur^1] reads finished last iter
        }
        const f16* phi_l = (const f16*)(smem + cur * 16384);
        const f16* g_l   = (const f16*)(smem + 32768 + cur * 20480);

        // S^T = phi_tile . theta^T : thread holds S[k=16to+4q+r][qrow=l15]
        f32x4 sT[2];
        sT[0] = (f32x4){0.f, 0.f, 0.f, 0.f};
        sT[1] = (f32x4){0.f, 0.f, 0.f, 0.f};
        #pragma unroll
        for (int kk = 0; kk < 8; ++kk) {
            int c = kk * 4 + q;
            int pos = (c & 24) | ((c ^ (l15 & 7)) & 7);
            #pragma unroll
            for (int to = 0; to < 2; ++to) {
                f16x8 af = *(const f16x8*)(phi_l + (16 * to + l15) * 256 + pos * 8);
                sT[to] = __builtin_amdgcn_mfma_f32_16x16x32_f16(af, th[kk], sT[to], 0, 0, 0);
            }
        }

        // online softmax: q-row l15 lives on this thread (8 vals) + 3 q-peers
        float tm = fmaxf(
            fmaxf(fmaxf(sT[0][0], sT[0][1]), fmaxf(sT[0][2], sT[0][3])),
            fmaxf(fmaxf(sT[1][0], sT[1][1]), fmaxf(sT[1][2], sT[1][3])));
        tm = fmaxf(tm, __shfl_xor(tm, 16));
        tm = fmaxf(tm, __shfl_xor(tm, 32));
        float mnew  = fmaxf(m_run, tm);
        float alpha = __expf(m_run - mnew);
        float rs = 0.f;
        #pragma unroll
        for (int to = 0; to < 2; ++to)
            #pragma unroll
            for (int r = 0; r < 4; ++r) {
                float p = __expf(sT[to][r] - mnew);
                sT[to][r] = p;
                rs += p;
            }
        rs += __shfl_xor(rs, 16);
        rs += __shfl_xor(rs, 32);
        l_run = l_run * alpha + rs;
        m_run = mnew;

        // P -> p_lds (wave-private rows; packed b64 writes, balanced banks)
        #pragma unroll
        for (int to = 0; to < 2; ++to) {
            f16x4 pk = { (f16)sT[to][0], (f16)sT[to][1], (f16)sT[to][2], (f16)sT[to][3] };
            *(f16x4*)(p_lds + (16 * w + l15) * 40 + 16 * to + 4 * q) = pk;
        }

        // rescale yacc rows (row of yacc[*][r] is q-row 4q+r)
        #pragma unroll
        for (int r = 0; r < 4; ++r) {
            float ar = __shfl(alpha, (lane & 48) | (4 * q + r));
            if (ar != 1.0f) {
                #pragma unroll
                for (int tco = 0; tco < 16; ++tco) yacc[tco][r] *= ar;
            }
        }

        // stage next g into idle buffer (vmcnt covered by S+softmax above)
        if (it < 63) write_g(cur ^ 1);

        // PV: A = P (k = 0..31), B = g tile (padded rows, conflict-free)
        f16x8 pa = *(const f16x8*)(p_lds + (16 * w + l15) * 40 + q * 8);
        #pragma unroll
        for (int tco = 0; tco < 16; ++tco) {
            f16x8 gfr = *(const f16x8*)(g_l + (16 * tco + l15) * 40 + q * 8);
            yacc[tco] = __builtin_amdgcn_mfma_f32_16x16x32_f16(pa, gfr, yacc[tco], 0, 0, 0);
        }

        __syncthreads();   // readers done + phi gld16 drained
    }

    // epilogue: y = yacc / l, staged through smem base (plain [64][256])
    float linv = 1.0f / l_run;   // for q-row l15
    f16* e_lds = (f16*)smem;
    #pragma unroll
    for (int r = 0; r < 4; ++r) {
        float iv = __shfl(linv, (lane & 48) | (4 * q + r));
        #pragma unroll
        for (int tco = 0; tco < 16; ++tco)
            e_lds[(16 * w + 4 * q + r) * 256 + 16 * tco + l15] =
                (f16)(yacc[tco][r] * iv);
    }
    __syncthreads();
    f16* dst = y + ((size_t)b * NSP + n0) * CIN;
    for (int k2 = 0; k2 < 8; ++k2) {
        int id = t + 256 * k2;
        *(f16x8*)(dst + id * 8) = *(const f16x8*)(e_lds + id * 8);
    }
}

// ---------------------------------------------------------------------------
// K3: Z = w_w . y^T + BN + residual, k_qkv m97 structure.
// Tile 64n x 256c, K=CIN=256 in 4 BK=64 steps, gld16 -> swizzled LDS for
// BOTH operands. grid (N/64, C/256, B) = (32,4,16).
// ---------------------------------------------------------------------------
__global__ __launch_bounds__(256, 3) void k_out(
    const f16* __restrict__ yv, const f16* __restrict__ ww,
    const float* __restrict__ inv, const float* __restrict__ off,
    const float* __restrict__ x, float* __restrict__ out)
{
    __shared__ char smem[40960];
    f16*   a_lds = (f16*)smem;            // [64][64]  y tile, swizzled (8 KB)
    f16*   b_lds = (f16*)(smem + 8192);   // [256][64] w tile, swizzled (32 KB)
    float* z_lds = (float*)smem;          // [64][68] f32 bounce (17.4 KB, alias)
    int t = threadIdx.x;
    int w = t >> 6, lane = t & 63, l15 = lane & 15, q = lane >> 4;
    int sw = l15 & 7;
    int n0 = blockIdx.x * 64, cb = blockIdx.y * 256, b = blockIdx.z;

    const f16* yA = yv + ((size_t)b * NSP + n0) * CIN;
    const f16* W  = ww + (size_t)cb * CIN;

    int rA  = lane >> 3;             // row-in-window 0..7
    int ccs = (lane & 7) ^ rA;       // swizzled global chunk for this lane

    f32x4 acc[4][4];
    #pragma unroll
    for (int i = 0; i < 4; ++i)
        #pragma unroll
        for (int j = 0; j < 4; ++j) acc[i][j] = (f32x4){0.f, 0.f, 0.f, 0.f};

    for (int it = 0; it < 4; ++it) {
        #pragma unroll
        for (int i = 0; i < 2; ++i) {
            int win = w * 2 + i;
            int n = win * 8 + rA;
            gld16((char*)a_lds + win * 1024,
                  yA + (size_t)n * CIN + it * 64 + ccs * 8);
        }
        #pragma unroll
        for (int i = 0; i < 8; ++i) {
            int win = w * 8 + i;
            int o = win * 8 + rA;
            gld16((char*)b_lds + win * 1024,
                  W + (size_t)o * CIN + it * 64 + ccs * 8);
        }
        __syncthreads();

        #pragma unroll
        for (int kl = 0; kl < 2; ++kl) {
            int c16 = kl * 4 + q;
            int pos = (c16 ^ sw) & 7;
            f16x8 af[4], bfr[4];
            #pragma unroll
            for (int tn = 0; tn < 4; ++tn)
                af[tn] = *(const f16x8*)(a_lds + (16 * tn + l15) * 64 + pos * 8);
            #pragma unroll
            for (int to = 0; to < 4; ++to)
                bfr[to] = *(const f16x8*)(b_lds + (64 * w + 16 * to + l15) * 64 + pos * 8);
            #pragma unroll
            for (int tn = 0; tn < 4; ++tn)
                #pragma unroll
                for (int to = 0; to < 4; ++to)
                    acc[tn][to] = __builtin_amdgcn_mfma_f32_16x16x32_f16(
                        af[tn], bfr[to], acc[tn][to], 0, 0, 0);
        }
        __syncthreads();
    }

    // ---- epilogue: 4 slabs over `to` (c-fragment); z bounce for coalescing.
    float4 xv[4];
    #pragma unroll
    for (int k2 = 0; k2 < 4; ++k2) {
        int f = t + 256 * k2;
        int zrr = f >> 4, nn4 = f & 15;
        int c = cb + 64 * (zrr >> 4) + (zrr & 15);   // to = 0
        xv[k2] = *(const float4*)(x + ((size_t)b * CH + c) * NSP + n0 + nn4 * 4);
    }

    #pragma unroll
    for (int to = 0; to < 4; ++to) {
        #pragma unroll
        for (int tn = 0; tn < 4; ++tn)
            #pragma unroll
            for (int r = 0; r < 4; ++r)
                z_lds[(16 * w + l15) * 68 + 16 * tn + 4 * q + r] = acc[tn][to][r];
        __syncthreads();

        float4 nxt[4];
        if (to < 3) {
            #pragma unroll
            for (int k2 = 0; k2 < 4; ++k2) {
                int f = t + 256 * k2;
                int zrr = f >> 4, nn4 = f & 15;
                int c = cb + 64 * (zrr >> 4) + 16 * (to + 1) + (zrr & 15);
                nxt[k2] = *(const float4*)(x + ((size_t)b * CH + c) * NSP + n0 + nn4 * 4);
            }
        }

        #pragma unroll
        for (int k2 = 0; k2 < 4; ++k2) {
            int f = t + 256 * k2;
            int zrr = f >> 4, nn4 = f & 15;
            int c = cb + 64 * (zrr >> 4) + 16 * to + (zrr & 15);
            float4 z = *(const float4*)(z_lds + zrr * 68 + nn4 * 4);
            float iv = inv[c], ov = off[c];
            size_t idx = ((size_t)b * CH + c) * NSP + n0 + nn4 * 4;
            float4 o;
            o.x = z.x * iv + ov + xv[k2].x;
            o.y = z.y * iv + ov + xv[k2].y;
            o.z = z.z * iv + ov + xv[k2].z;
            o.w = z.w * iv + ov + xv[k2].w;
            *(float4*)(out + idx) = o;
        }

        if (to < 3) {
            #pragma unroll
            for (int k2 = 0; k2 < 4; ++k2) xv[k2] = nxt[k2];
            __syncthreads();   // z reads done before next slab's writes
        }
    }
}

// ---------------------------------------------------------------------------
extern "C" void kernel_launch(void* const* d_in, const int* in_sizes, int n_in,
                              void* d_out, int out_size, void* d_ws, size_t ws_size,
                              hipStream_t stream)
{
    const float* x     = (const float*)d_in[0];
    const float* tw    = (const float*)d_in[1];
    const float* tb    = (const float*)d_in[2];
    const float* pw    = (const float*)d_in[3];
    const float* pb    = (const float*)d_in[4];
    const float* gw    = (const float*)d_in[5];
    const float* gb_   = (const float*)d_in[6];
    const float* ww    = (const float*)d_in[7];
    const float* wb    = (const float*)d_in[8];
    const float* gamma = (const float*)d_in[9];
    const float* beta  = (const float*)d_in[10];
    const float* mean  = (const float*)d_in[11];
    const float* var   = (const float*)d_in[12];
    float* out = (float*)d_out;

    char* ws = (char*)d_ws;
    f16* xT    = (f16*)ws;                    //  67108864 B
    f16* theta = (f16*)(ws + 67108864);       //  16777216 B
    f16* phiT  = (f16*)(ws + 83886080);       //  16777216 B
    f16* gT    = (f16*)(ws + 100663296);      //  16777216 B
    f16* yv    = (f16*)(ws + 117440512);      //  16777216 B
    f16* w_all = (f16*)(ws + 134217728);      //  4*524288 B
    float* inv  = (float*)(ws + 136314880);   //  4096 B
    float* offv = (float*)(ws + 136318976);   //  4096 B

    k_prep<<<4100, 256, 0, stream>>>(tw, pw, gw, ww, wb, gamma, beta, mean, var,
                                     w_all, inv, offv);
    k_transpose_x<<<dim3(32, 16, 16), 256, 0, stream>>>(x, xT);
    k_qkv<<<dim3(32, 16, 3), 256, 0, stream>>>(xT, w_all, tb, pb, gb_, theta, phiT, gT);
    k_attn<<<dim3(16, 32), 256, 0, stream>>>(theta, phiT, gT, yv);
    k_out<<<dim3(32, 4, 16), 256, 0, stream>>>(yv, w_all + 3 * 262144, inv, offv, x, out);
}